// Round 1
// baseline (1379.690 us; speedup 1.0000x reference)
//
#include <hip/hip_runtime.h>

#define NTOK 32768
#define HD   4096
#define EXP  64
#define KCAP 512
#define CAP  2048

static __device__ __forceinline__ unsigned f2key(float f) {
  unsigned b = __float_as_uint(f);
  return (b & 0x80000000u) ? ~b : (b ^ 0x80000000u);
}

// ---------------- zero workspace (hist + cnt) ----------------
__global__ void zero_kernel(int* __restrict__ p, int n) {
  int i = blockIdx.x * 256 + threadIdx.x;
  if (i < n) p[i] = 0;
}

// ---------------- GEMM: logits[N,64] = x[N,4096] @ W[4096,64] ----------------
// grid 512 blocks x 256 threads; block does 64 rows x 64 cols; K-chunks of 64.
__global__ __launch_bounds__(256) void gemm_kernel(const float* __restrict__ x,
                                                   const float* __restrict__ Wg,
                                                   float* __restrict__ logits) {
  __shared__ float xs[64][65];   // [k][m], pad 65 -> 2-way bank aliasing (free)
  __shared__ float ws[64][64];   // [k][n]
  const int tid  = threadIdx.x;
  const int lane = tid & 63;
  const int wv   = tid >> 6;     // wave id 0..3
  const int n0   = wv * 16;      // this wave's 16 columns
  const int mbase = blockIdx.x * 64;

  float acc[16];
#pragma unroll
  for (int j = 0; j < 16; ++j) acc[j] = 0.f;

  const int lr = tid >> 4;       // 0..15 row group for x staging
  const int lc = tid & 15;       // float4 within 64-float row chunk

  for (int kb = 0; kb < HD; kb += 64) {
    // stage x tile 64 rows x 64 k, transposed into xs[k][m]
#pragma unroll
    for (int p = 0; p < 4; ++p) {
      const int row = lr + p * 16;
      const float4 v = *(const float4*)(x + (size_t)(mbase + row) * HD + kb + lc * 4);
      xs[lc * 4 + 0][row] = v.x;
      xs[lc * 4 + 1][row] = v.y;
      xs[lc * 4 + 2][row] = v.z;
      xs[lc * 4 + 3][row] = v.w;
    }
    // stage W chunk 64 k x 64 n (contiguous)
    {
      const float4* Wv  = (const float4*)(Wg + (size_t)kb * 64);
      float4*       wsv = (float4*)(&ws[0][0]);
#pragma unroll
      for (int p = 0; p < 4; ++p) wsv[tid + p * 256] = Wv[tid + p * 256];
    }
    __syncthreads();

#pragma unroll 16
    for (int kk = 0; kk < 64; ++kk) {
      const float xv = xs[kk][lane];
      const float* wr = &ws[kk][n0];
      const float4 w0 = *(const float4*)(wr);
      const float4 w1 = *(const float4*)(wr + 4);
      const float4 w2 = *(const float4*)(wr + 8);
      const float4 w3 = *(const float4*)(wr + 12);
      acc[0]  = fmaf(xv, w0.x, acc[0]);
      acc[1]  = fmaf(xv, w0.y, acc[1]);
      acc[2]  = fmaf(xv, w0.z, acc[2]);
      acc[3]  = fmaf(xv, w0.w, acc[3]);
      acc[4]  = fmaf(xv, w1.x, acc[4]);
      acc[5]  = fmaf(xv, w1.y, acc[5]);
      acc[6]  = fmaf(xv, w1.z, acc[6]);
      acc[7]  = fmaf(xv, w1.w, acc[7]);
      acc[8]  = fmaf(xv, w2.x, acc[8]);
      acc[9]  = fmaf(xv, w2.y, acc[9]);
      acc[10] = fmaf(xv, w2.z, acc[10]);
      acc[11] = fmaf(xv, w2.w, acc[11]);
      acc[12] = fmaf(xv, w3.x, acc[12]);
      acc[13] = fmaf(xv, w3.y, acc[13]);
      acc[14] = fmaf(xv, w3.z, acc[14]);
      acc[15] = fmaf(xv, w3.w, acc[15]);
    }
    __syncthreads();
  }

  float* orow = logits + (size_t)(mbase + lane) * 64 + n0;
  *(float4*)(orow + 0)  = make_float4(acc[0], acc[1], acc[2], acc[3]);
  *(float4*)(orow + 4)  = make_float4(acc[4], acc[5], acc[6], acc[7]);
  *(float4*)(orow + 8)  = make_float4(acc[8], acc[9], acc[10], acc[11]);
  *(float4*)(orow + 12) = make_float4(acc[12], acc[13], acc[14], acc[15]);
}

// ---------------- per-expert 256-bin histogram of top-8 key bits ----------------
// 512 blocks: blocks [0,256) handle experts 0..31, [256,512) experts 32..63.
__global__ __launch_bounds__(256) void hist_kernel(const float* __restrict__ logits,
                                                   int* __restrict__ ghist) {
  __shared__ int lh[32 * 256];
  for (int i = threadIdx.x; i < 32 * 256; i += 256) lh[i] = 0;
  __syncthreads();
  const int half  = blockIdx.x >> 8;
  const int ebase = half << 5;
  const size_t base = (size_t)(blockIdx.x & 255) * 8192;
  for (int j = 0; j < 32; ++j) {
    const size_t idx = base + j * 256 + threadIdx.x;
    const int e = (int)(idx & 63);
    if ((e >> 5) == half) {
      const unsigned key = f2key(logits[idx]);
      atomicAdd(&lh[(e - ebase) * 256 + (int)(key >> 24)], 1);
    }
  }
  __syncthreads();
  for (int i = threadIdx.x; i < 32 * 256; i += 256) {
    const int c = lh[i];
    if (c) atomicAdd(&ghist[ebase * 256 + i], c);
  }
}

// ---------------- pick the bin containing the 512th-largest ----------------
__global__ void binsel_kernel(const int* __restrict__ ghist,
                              int* __restrict__ bstar, int* __restrict__ above) {
  const int e = threadIdx.x;
  const int* h = ghist + e * 256;
  int cum = 0, sel = 0;
  for (int b = 255; b >= 0; --b) {
    cum += h[b];
    if (cum >= KCAP) { sel = b; break; }
  }
  bstar[e] = sel;
  above[e] = cum - h[sel];   // count strictly above the selected bin
}

// ---------------- compact in-bin candidates (key, token) per expert ----------------
__global__ __launch_bounds__(256) void compact_kernel(const float* __restrict__ logits,
                                                      const int* __restrict__ bstar,
                                                      int* __restrict__ cnt,
                                                      unsigned* __restrict__ ckey,
                                                      int* __restrict__ cidx) {
  __shared__ int bs[64];
  if (threadIdx.x < 64) bs[threadIdx.x] = bstar[threadIdx.x];
  __syncthreads();
  const size_t base = (size_t)blockIdx.x * 8192;
  for (int j = 0; j < 32; ++j) {
    const size_t idx = base + j * 256 + threadIdx.x;
    const unsigned key = f2key(logits[idx]);
    const int e = (int)(idx & 63);
    if ((int)(key >> 24) == bs[e]) {
      const int p = atomicAdd(&cnt[e], 1);
      if (p < CAP) {
        ckey[(size_t)e * CAP + p] = key;
        cidx[(size_t)e * CAP + p] = (int)(idx >> 6);
      }
    }
  }
}

// ---------------- exact tau + tie cutoff per expert (radix select in LDS) ----------------
__global__ __launch_bounds__(256) void refine_kernel(const unsigned* __restrict__ ckey,
                                                     const int* __restrict__ cidx,
                                                     const int* __restrict__ cnt,
                                                     const int* __restrict__ bstar,
                                                     const int* __restrict__ above,
                                                     float* __restrict__ tau,
                                                     int* __restrict__ cutoff) {
  __shared__ int h[256];
  __shared__ int sm_sel, sm_m, eqcnt;
  __shared__ int eqidx[256];
  const int e = blockIdx.x;
  const int n = min(cnt[e], CAP);
  const unsigned* keys = ckey + (size_t)e * CAP;
  const int* idxs = cidx + (size_t)e * CAP;
  int m = KCAP - above[e];                    // rank to find within the bin (>=1)
  unsigned prefix = ((unsigned)bstar[e]) << 24;
  unsigned mask = 0xFF000000u;

  for (int shift = 16; shift >= 0; shift -= 8) {
    h[threadIdx.x] = 0;
    __syncthreads();
    for (int i = threadIdx.x; i < n; i += 256) {
      const unsigned k = keys[i];
      if ((k & mask) == prefix) atomicAdd(&h[(int)((k >> shift) & 0xFFu)], 1);
    }
    __syncthreads();
    if (threadIdx.x == 0) {
      int cum = 0, sel = 0;
      for (int b = 255; b >= 0; --b) {
        cum += h[b];
        if (cum >= m) { sel = b; break; }
      }
      sm_sel = sel;
      sm_m = m - (cum - h[sel]);
    }
    __syncthreads();
    prefix |= ((unsigned)sm_sel) << shift;
    mask   |= 0xFFu << shift;
    m = sm_m;
    __syncthreads();
  }
  // prefix == exact key of the 512th-largest; m == #eq-keys to accept (smallest token idx first)
  if (threadIdx.x == 0) eqcnt = 0;
  __syncthreads();
  for (int i = threadIdx.x; i < n; i += 256) {
    if (keys[i] == prefix) {
      const int p = atomicAdd(&eqcnt, 1);
      if (p < 256) eqidx[p] = idxs[i];
    }
  }
  __syncthreads();
  if (threadIdx.x == 0) {
    int cut;
    const int cE = min(eqcnt, 256);
    if (eqcnt <= m) {
      cut = NTOK;                       // all ties accepted
    } else {
      cut = NTOK;                       // find m-th smallest token index among ties
      for (int i = 0; i < cE; ++i) {
        int c = 0;
        for (int j = 0; j < cE; ++j) c += (eqidx[j] <= eqidx[i]) ? 1 : 0;
        if (c == m) { cut = eqidx[i]; break; }
      }
    }
    cutoff[e] = cut;
    const unsigned k = prefix;
    const unsigned b = (k & 0x80000000u) ? (k ^ 0x80000000u) : ~k;
    tau[e] = __uint_as_float(b);
  }
}

// ---------------- assignment: one wave per token ----------------
__global__ __launch_bounds__(256) void assign_kernel(const float* __restrict__ logits,
                                                     const float* __restrict__ tau,
                                                     const int* __restrict__ cutoff,
                                                     float* __restrict__ wout,
                                                     float* __restrict__ iout) {
  const int gt = blockIdx.x * 256 + threadIdx.x;
  const int t = gt >> 6;
  const int lane = threadIdx.x & 63;
  const float v = logits[(size_t)t * 64 + lane];
  const float te = tau[lane];
  const int co = cutoff[lane];
  const bool picked = (v > te) || (v == te && t <= co);

  float fv = v;                       int fe = lane;        // fallback argmax (first max)
  float av = picked ? v : -INFINITY;  int ae = picked ? lane : 64;
#pragma unroll
  for (int off = 32; off > 0; off >>= 1) {
    const float ofv = __shfl_xor(fv, off);
    const int   ofe = __shfl_xor(fe, off);
    if (ofv > fv || (ofv == fv && ofe < fe)) { fv = ofv; fe = ofe; }
    const float oav = __shfl_xor(av, off);
    const int   oae = __shfl_xor(ae, off);
    if (oav > av || (oav == av && oae < ae)) { av = oav; ae = oae; }
  }
  if (lane == 0) {
    float w; int ei;
    if (ae < 64) { w = av; ei = ae; }        // assigned by expert-choice
    else         { w = fv; ei = fe; }        // fallback
    wout[t] = w;
    iout[t] = (float)ei;
  }
}

extern "C" void kernel_launch(void* const* d_in, const int* in_sizes, int n_in,
                              void* d_out, int out_size, void* d_ws, size_t ws_size,
                              hipStream_t stream) {
  const float* x  = (const float*)d_in[0];
  const float* Wg = (const float*)d_in[1];
  float* out    = (float*)d_out;
  float* wout   = out;
  float* iout   = out + NTOK;
  float* logits = out + 2 * NTOK;

  int* ws = (int*)d_ws;
  int*      ghist  = ws;                          // 64*256 = 16384 ints
  int*      cnt    = ws + 16384;                  // 64
  int*      bstar  = ws + 16448;                  // 64
  int*      above  = ws + 16512;                  // 64
  float*    tau    = (float*)(ws + 16576);        // 64
  int*      cutoff = ws + 16640;                  // 64
  unsigned* ckey   = (unsigned*)(ws + 16704);     // 64*CAP
  int*      cidx   = ws + 16704 + EXP * CAP;      // 64*CAP

  hipLaunchKernelGGL(zero_kernel, dim3(65), dim3(256), 0, stream, ws, 16448);
  hipLaunchKernelGGL(gemm_kernel, dim3(NTOK / 64), dim3(256), 0, stream, x, Wg, logits);
  hipLaunchKernelGGL(hist_kernel, dim3(512), dim3(256), 0, stream, logits, ghist);
  hipLaunchKernelGGL(binsel_kernel, dim3(1), dim3(64), 0, stream, ghist, bstar, above);
  hipLaunchKernelGGL(compact_kernel, dim3(256), dim3(256), 0, stream, logits, bstar, cnt, ckey, cidx);
  hipLaunchKernelGGL(refine_kernel, dim3(64), dim3(256), 0, stream, ckey, cidx, cnt, bstar, above, tau, cutoff);
  hipLaunchKernelGGL(assign_kernel, dim3(NTOK / 4), dim3(256), 0, stream, logits, tau, cutoff, wout, iout);
}

// Round 2
// 1233.002 us; speedup vs baseline: 1.1190x; 1.1190x over previous
//
#include <hip/hip_runtime.h>

#define NTOK 32768
#define HD   4096
#define EXP  64
#define KCAP 512
#define CAP  2048

static __device__ __forceinline__ unsigned f2key(float f) {
  unsigned b = __float_as_uint(f);
  return (b & 0x80000000u) ? ~b : (b ^ 0x80000000u);
}

// ---------------- GEMM: logits[N,64] = x[N,4096] @ W[4096,64] ----------------
// 512 blocks x 256 threads; block = 64 rows; wave = 64 rows x 16 cols; W via
// wave-uniform (scalar) loads -> SGPRs; x staged transposed in LDS.
__global__ __launch_bounds__(256) void gemm_kernel(const float* __restrict__ x,
                                                   const float* __restrict__ Wg,
                                                   float* __restrict__ logits,
                                                   float* __restrict__ logitsT,
                                                   const int writeT) {
  __shared__ float xs[64][65];   // [k][m], pad -> 2-way bank aliasing (free)
  const int tid  = threadIdx.x;
  const int lane = tid & 63;
  const int wv   = tid >> 6;
  // force wave-uniform column base so W loads scalarize to s_load
  const int n0   = __builtin_amdgcn_readfirstlane(wv << 4);
  const int mbase = blockIdx.x * 64;

  float acc[16];
#pragma unroll
  for (int j = 0; j < 16; ++j) acc[j] = 0.f;

  const int lr = tid >> 4;   // 0..15
  const int lc = tid & 15;   // float4 slot

  for (int kb = 0; kb < HD; kb += 64) {
    __syncthreads();
#pragma unroll
    for (int p = 0; p < 4; ++p) {
      const int row = lr + p * 16;
      const float4 v = *(const float4*)(x + (size_t)(mbase + row) * HD + kb + lc * 4);
      xs[lc * 4 + 0][row] = v.x;
      xs[lc * 4 + 1][row] = v.y;
      xs[lc * 4 + 2][row] = v.z;
      xs[lc * 4 + 3][row] = v.w;
    }
    __syncthreads();

#pragma unroll 4
    for (int kk = 0; kk < 64; ++kk) {
      const float xv = xs[kk][lane];
      const float* __restrict__ wr = Wg + (size_t)(kb + kk) * 64 + n0;  // wave-uniform
      const float4 w0 = *(const float4*)(wr);
      const float4 w1 = *(const float4*)(wr + 4);
      const float4 w2 = *(const float4*)(wr + 8);
      const float4 w3 = *(const float4*)(wr + 12);
      acc[0]  = fmaf(xv, w0.x, acc[0]);
      acc[1]  = fmaf(xv, w0.y, acc[1]);
      acc[2]  = fmaf(xv, w0.z, acc[2]);
      acc[3]  = fmaf(xv, w0.w, acc[3]);
      acc[4]  = fmaf(xv, w1.x, acc[4]);
      acc[5]  = fmaf(xv, w1.y, acc[5]);
      acc[6]  = fmaf(xv, w1.z, acc[6]);
      acc[7]  = fmaf(xv, w1.w, acc[7]);
      acc[8]  = fmaf(xv, w2.x, acc[8]);
      acc[9]  = fmaf(xv, w2.y, acc[9]);
      acc[10] = fmaf(xv, w2.z, acc[10]);
      acc[11] = fmaf(xv, w2.w, acc[11]);
      acc[12] = fmaf(xv, w3.x, acc[12]);
      acc[13] = fmaf(xv, w3.y, acc[13]);
      acc[14] = fmaf(xv, w3.z, acc[14]);
      acc[15] = fmaf(xv, w3.w, acc[15]);
    }
  }

  float* orow = logits + (size_t)(mbase + lane) * 64 + n0;
  *(float4*)(orow + 0)  = make_float4(acc[0], acc[1], acc[2], acc[3]);
  *(float4*)(orow + 4)  = make_float4(acc[4], acc[5], acc[6], acc[7]);
  *(float4*)(orow + 8)  = make_float4(acc[8], acc[9], acc[10], acc[11]);
  *(float4*)(orow + 12) = make_float4(acc[12], acc[13], acc[14], acc[15]);

  if (writeT) {
#pragma unroll
    for (int j = 0; j < 16; ++j)
      logitsT[(size_t)(n0 + j) * NTOK + mbase + lane] = acc[j];   // coalesced
  }
}

// ---------------- per-expert exact top-512 threshold, all in LDS ----------------
// 64 blocks (one per expert) x 256 threads. Two passes over the expert's column,
// 256-bin hist -> bin select -> in-bin compaction -> 24-bit radix refine -> ties.
__global__ __launch_bounds__(256) void topk_kernel(const float* __restrict__ colbase,
                                                   const long long cstride,
                                                   float* __restrict__ tau,
                                                   int* __restrict__ cutoff) {
  __shared__ int hist[256];
  __shared__ unsigned ckey[CAP];
  __shared__ int cidx[CAP];
  __shared__ int s_sel, s_above, s_cnt, s_m, s_eqcnt;
  __shared__ int eqidx[128];
  const int tid = threadIdx.x;
  const int e = blockIdx.x;
  const float* __restrict__ col =
      colbase + (cstride == 1 ? (long long)e * NTOK : (long long)e);

  hist[tid] = 0;
  if (tid == 0) { s_cnt = 0; s_eqcnt = 0; }
  __syncthreads();

  // pass 1: 256-bin histogram of top-8 key bits
  for (int i = tid; i < NTOK; i += 256) {
    const unsigned k = f2key(col[(long long)i * cstride]);
    atomicAdd(&hist[k >> 24], 1);
  }
  __syncthreads();
  if (tid == 0) {
    int cum = 0, sel = 0, ab = 0;
    for (int b = 255; b >= 0; --b) {            // no break -> pipelined LDS reads
      const int h = hist[b]; const int nc = cum + h;
      if (cum < KCAP && nc >= KCAP) { sel = b; ab = cum; }
      cum = nc;
    }
    s_sel = sel; s_above = ab;
  }
  __syncthreads();
  const int selbin = s_sel;
  int m = KCAP - s_above;                       // rank within selected bin, >=1

  // pass 2: compact in-bin candidates to LDS
  for (int i = tid; i < NTOK; i += 256) {
    const unsigned k = f2key(col[(long long)i * cstride]);
    if ((int)(k >> 24) == selbin) {
      const int p = atomicAdd(&s_cnt, 1);
      if (p < CAP) { ckey[p] = k; cidx[p] = i; }
    }
  }
  __syncthreads();
  const int n = min(s_cnt, CAP);

  // radix refine remaining 24 bits
  unsigned prefix = ((unsigned)selbin) << 24;
  unsigned mask = 0xFF000000u;
  for (int shift = 16; shift >= 0; shift -= 8) {
    __syncthreads();
    hist[tid] = 0;
    __syncthreads();
    for (int i = tid; i < n; i += 256) {
      const unsigned k = ckey[i];
      if ((k & mask) == prefix) atomicAdd(&hist[(k >> shift) & 0xFFu], 1);
    }
    __syncthreads();
    if (tid == 0) {
      int cum = 0, sel = 0, ab = 0;
      for (int b = 255; b >= 0; --b) {
        const int h = hist[b]; const int nc = cum + h;
        if (cum < m && nc >= m) { sel = b; ab = cum; }
        cum = nc;
      }
      s_sel = sel; s_m = m - ab;
    }
    __syncthreads();
    prefix |= ((unsigned)s_sel) << shift;
    mask   |= 0xFFu << shift;
    m = s_m;
  }

  // ties: accept the m smallest token indices among keys == prefix
  __syncthreads();
  for (int i = tid; i < n; i += 256) {
    if (ckey[i] == prefix) {
      const int p = atomicAdd(&s_eqcnt, 1);
      if (p < 128) eqidx[p] = cidx[i];
    }
  }
  __syncthreads();
  if (tid == 0) {
    int cut = NTOK;                             // all ties accepted
    const int c = min(s_eqcnt, 128);
    if (s_eqcnt > m) {
      for (int i = 0; i < c; ++i) {
        int r = 0;
        for (int j = 0; j < c; ++j) r += (eqidx[j] <= eqidx[i]) ? 1 : 0;
        if (r == m) { cut = eqidx[i]; break; }
      }
    }
    cutoff[e] = cut;
    const unsigned kk = prefix;
    const unsigned b = (kk & 0x80000000u) ? (kk ^ 0x80000000u) : ~kk;
    tau[e] = __uint_as_float(b);
  }
}

// ---------------- assignment: one wave per token ----------------
__global__ __launch_bounds__(256) void assign_kernel(const float* __restrict__ logits,
                                                     const float* __restrict__ tau,
                                                     const int* __restrict__ cutoff,
                                                     float* __restrict__ wout,
                                                     float* __restrict__ iout) {
  const int gt = blockIdx.x * 256 + threadIdx.x;
  const int t = gt >> 6;
  const int lane = threadIdx.x & 63;
  const float v = logits[(size_t)t * 64 + lane];
  const float te = tau[lane];
  const int co = cutoff[lane];
  const bool picked = (v > te) || (v == te && t <= co);

  float fv = v;                       int fe = lane;        // fallback argmax (first max)
  float av = picked ? v : -INFINITY;  int ae = picked ? lane : 64;
#pragma unroll
  for (int off = 32; off > 0; off >>= 1) {
    const float ofv = __shfl_xor(fv, off);
    const int   ofe = __shfl_xor(fe, off);
    if (ofv > fv || (ofv == fv && ofe < fe)) { fv = ofv; fe = ofe; }
    const float oav = __shfl_xor(av, off);
    const int   oae = __shfl_xor(ae, off);
    if (oav > av || (oav == av && oae < ae)) { av = oav; ae = oae; }
  }
  if (lane == 0) {
    float w; int ei;
    if (ae < 64) { w = av; ei = ae; }
    else         { w = fv; ei = fe; }
    wout[t] = w;
    iout[t] = (float)ei;
  }
}

extern "C" void kernel_launch(void* const* d_in, const int* in_sizes, int n_in,
                              void* d_out, int out_size, void* d_ws, size_t ws_size,
                              hipStream_t stream) {
  const float* x  = (const float*)d_in[0];
  const float* Wg = (const float*)d_in[1];
  float* out    = (float*)d_out;
  float* wout   = out;
  float* iout   = out + NTOK;
  float* logits = out + 2 * NTOK;

  float* tau     = (float*)d_ws;
  int*   cutoff  = (int*)d_ws + 64;
  float* logitsT = (float*)d_ws + 256;
  const int useT = (ws_size >= 256 * 4 + (size_t)NTOK * EXP * 4) ? 1 : 0;

  hipLaunchKernelGGL(gemm_kernel, dim3(NTOK / 64), dim3(256), 0, stream,
                     x, Wg, logits, logitsT, useT);
  hipLaunchKernelGGL(topk_kernel, dim3(EXP), dim3(256), 0, stream,
                     useT ? (const float*)logitsT : (const float*)logits,
                     useT ? 1LL : 64LL, tau, cutoff);
  hipLaunchKernelGGL(assign_kernel, dim3(NTOK / 4), dim3(256), 0, stream,
                     logits, tau, cutoff, wout, iout);
}